// Round 10
// baseline (255.116 us; speedup 1.0000x reference)
//
#include <hip/hip_runtime.h>
#include <stdint.h>

#define NL   12
#define PTOT 32936
#define LMB  32778
#define NCH  515           // ceil(PTOT/64) words of positivity bits
#define NCHP 520           // padded LDS words
#define NGRP 129           // ceil(NCH/4) 256-elem groups (64 float4 / group)
#define BMW  (NGRP * 4)    // 516 contiguous-bit words
#define TPAD (NGRP * 256)  // 33024 padded table elems
#define NSEG 445           // 12 layers * 37 segments + 1 LM segment
#define TPB  512           // threads per block (8 waves)
#define NWV  (TPB / 64)
#define NITER ((NGRP + NWV - 1) / NWV)   // 17 groups per wave (statically unrolled)

typedef float vf4 __attribute__((ext_vector_type(4)));

__device__ __constant__ int c_base[NL] = {0,86,653,1701,3230,5240,7731,10703,14156,18090,22505,27401};

__device__ __forceinline__ uint64_t ext(const uint64_t* P, uint32_t off) {
  uint32_t w = off >> 6, s = off & 63;
  uint64_t lo = P[w], hi = P[w + 1];
  return s ? ((lo >> s) | (hi << (64 - s))) : lo;
}

__device__ __forceinline__ uint64_t rbit(uint64_t r0, uint64_t r1, uint64_t r2, uint32_t idx) {
  uint64_t w = idx < 64 ? r0 : (idx < 128 ? r1 : r2);
  return (w >> (idx & 63)) & 1ull;
}

// register-resident ext over the 158-bit live vector (bits >=192 implied 0)
__device__ __forceinline__ uint64_t rext(uint64_t a0, uint64_t a1, uint64_t a2, uint32_t off) {
  uint32_t w = off >> 6, s = off & 63;
  uint64_t lo = (w == 0) ? a0 : ((w == 1) ? a1 : ((w == 2) ? a2 : 0ull));
  uint64_t hi = (w == 0) ? a1 : ((w == 1) ? a2 : 0ull);
  return s ? ((lo >> s) | (hi << (64 - s))) : lo;
}

__device__ __forceinline__ void orAt(uint64_t& r0, uint64_t& r1, uint64_t& r2,
                                     uint64_t val, uint32_t pos) {
  uint32_t w = pos >> 6, s = pos & 63;
  uint64_t lo = val << s;
  uint64_t hi = s ? (val >> (64 - s)) : 0ull;
  if (w == 0) { r0 |= lo; r1 |= hi; }
  else if (w == 1) { r1 |= lo; r2 |= hi; }
  else { r2 |= lo; }
}

__device__ __forceinline__ void maskLen(uint32_t len, uint64_t& m0, uint64_t& m1, uint64_t& m2) {
  m0 = (len >= 64) ? ~0ull : ((1ull << len) - 1ull);
  m1 = (len <= 64) ? 0ull : ((len >= 128) ? ~0ull : ((1ull << (len - 64)) - 1ull));
  m2 = (len <= 128) ? 0ull : ((1ull << (len - 128)) - 1ull);
}

__device__ __forceinline__ uint32_t ext12(uint64_t O0, uint64_t O1, uint64_t O2, uint32_t pos) {
  uint32_t w = pos >> 6, s = pos & 63;
  uint64_t lo = (w == 0) ? O0 : ((w == 1) ? O1 : O2);
  uint64_t hi = (w == 0) ? O1 : ((w == 1) ? O2 : 0ull);
  uint64_t v = s ? ((lo >> s) | (hi << (64 - s))) : lo;
  return (uint32_t)v & 0xFFFu;
}

// spread 16 bits to every 4th bit of a 64-bit word
__device__ __forceinline__ uint64_t spread4(uint64_t x) {
  x = (x | (x << 24)) & 0x000000FF000000FFull;
  x = (x | (x << 12)) & 0x000F000F000F000Full;
  x = (x | (x << 6))  & 0x0303030303030303ull;
  x = (x | (x << 3))  & 0x1111111111111111ull;
  return x;
}

// Per-param (prob', window) SoA tables.
__global__ void init_tables(const float* __restrict__ sp, float* __restrict__ pr,
                            float* __restrict__ wd) {
  int p = blockIdx.x * blockDim.x + threadIdx.x;
  if (p >= TPAD) return;
  if (p < PTOT) {
    float x = sp[p];
    float s = 1.0f / (1.0f + expf(-x));                 // sigmoid, fp32
    float w = __fmul_rn(s, __fsub_rn(1.0f, s));         // window = p*(1-p)
    float pv = __fadd_rn(__fmul_rn(w, s), __fmul_rn(__fsub_rn(1.0f, w), s));
    pr[p] = pv; wd[p] = w;
  } else {
    pr[p] = 0.0f; wd[p] = 1.0f;
  }
}

// ---- Fused kernel: one 512-thread block per row -----------------------------
// HBM traffic = read unif once + write out once (compulsory minimum).
// Phase A : 4-deep-prefetch stream: u -> m -> clip (kept in mv registers),
//           positivity ballots deinterleaved INLINE (lanes 0-3 spread4)
//           straight into sPos — phase B eliminated.
// Phase C : wave 0: forward reachability R, backward liveness O (O ⊆ R),
//           live = R & O.
// Phase D : per-segment shifted-window keep build.
// Phase F : select registered clipped value by keep bit, streaming store.
__global__ __launch_bounds__(TPB, 3) void fused_kernel(const float* __restrict__ unif,
                                                       const vf4* __restrict__ pr4,
                                                       const vf4* __restrict__ wd4,
                                                       float* __restrict__ out) {
  __shared__ uint64_t sPos[NCHP];    // contiguous positivity bits
  __shared__ uint64_t sKeep[NCHP];   // keep bits (built in D)
  __shared__ uint64_t sLv[4];        // live = R & O

  const int tid  = threadIdx.x;
  const int lane = tid & 63;
  const int wv   = tid >> 6;
  const int row  = blockIdx.x;
  const vf4* up4 = (const vf4*)(unif + (size_t)row * PTOT);
  vf4*       op4 = (vf4*)(out + (size_t)row * PTOT);

  vf4 mv[NITER];                     // per-thread registered CLIPPED m values
  vf4 ub[4], pb[2], wb[2];           // circular prefetch buffers (static idx)

#define LDU(K) do { int G_ = wv + (K) * NWV; if (G_ < NGRP) {                  \
    int e4_ = G_ * 64 + lane;                                                  \
    ub[(K) % 4] = (e4_ < (PTOT / 4)) ? up4[e4_] : (vf4){0.f,0.f,0.f,0.f}; } } while (0)
#define LDPW(K) do { int G_ = wv + (K) * NWV; if (G_ < NGRP) {                 \
    int e4_ = G_ * 64 + lane;                                                  \
    pb[(K) % 2] = pr4[e4_]; wb[(K) % 2] = wd4[e4_]; } } while (0)

  // ---- prologue: issue first loads, zero LDS while they fly ---------------
  LDU(0); LDU(1); LDU(2); LDU(3); LDPW(0); LDPW(1);
  for (int w = tid; w < NCHP; w += TPB) sKeep[w] = 0ull;
  for (int w = BMW + tid; w < NCHP; w += TPB) sPos[w] = 0ull;

  // ---- Phase A: stream + clip + ballot + inline deinterleave --------------
#pragma unroll
  for (int k = 0; k < NITER; ++k) {
    const int G = wv + k * NWV;                 // wave-uniform
    if (G < NGRP) {
      vf4 u = ub[k % 4], p = pb[k % 2], w = wb[k % 2];
      int e4 = G * 64 + lane;
      bool inb = e4 < (PTOT / 4);
      float m0 = __fadd_rn(__fdiv_rn(__fsub_rn(p.x, u.x), w.x), 0.5f);
      float m1 = __fadd_rn(__fdiv_rn(__fsub_rn(p.y, u.y), w.y), 0.5f);
      float m2 = __fadd_rn(__fdiv_rn(__fsub_rn(p.z, u.z), w.z), 0.5f);
      float m3 = __fadd_rn(__fdiv_rn(__fsub_rn(p.w, u.w), w.w), 0.5f);
      mv[k] = (vf4){fminf(fmaxf(m0, 0.0f), 1.0f), fminf(fmaxf(m1, 0.0f), 1.0f),
                    fminf(fmaxf(m2, 0.0f), 1.0f), fminf(fmaxf(m3, 0.0f), 1.0f)};
      uint64_t b0 = __ballot(inb && (m0 > 0.0f));
      uint64_t b1 = __ballot(inb && (m1 > 0.0f));
      uint64_t b2 = __ballot(inb && (m2 > 0.0f));
      uint64_t b3 = __ballot(inb && (m3 > 0.0f));
      if (lane < 4) {                          // inline deinterleave (was phase B)
        int q = lane;
        uint64_t v = spread4((b0 >> (16 * q)) & 0xFFFFull)
                   | (spread4((b1 >> (16 * q)) & 0xFFFFull) << 1)
                   | (spread4((b2 >> (16 * q)) & 0xFFFFull) << 2)
                   | (spread4((b3 >> (16 * q)) & 0xFFFFull) << 3);
        sPos[4 * G + q] = v;
      }
    }
    // consume-then-refill: slot (k+4)%4 == k%4, safe after use above
    if (k + 4 < NITER) LDU(k + 4);
    if (k + 2 < NITER) LDPW(k + 2);
  }
#undef LDU
#undef LDPW
  __syncthreads();

  // ---- Phase C: forward R then backward O on wave 0 -----------------------
  if (tid < 64) {
    uint64_t R0 = 3ull, R1 = 0ull, R2 = 0ull;
    const int g = lane;
#pragma unroll
    for (int L = 0; L < NL; ++L) {
      const int Vq = 2 + 13 * L;
      const int b  = c_base[L];
      bool pred = false;
      if (g < 36) {
        uint32_t off = (uint32_t)(b + g * Vq);
        uint64_t e0 = ext(sPos, off), e1 = ext(sPos, off + 64), e2 = ext(sPos, off + 128);
        pred = ((e0 & R0) | (e1 & R1) | (e2 & R2)) != 0ull;
      }
      uint64_t bal = __ballot(pred);
      uint64_t ar  = bal & (bal >> 12) & (bal >> 24) & 0xFFFull;
      orAt(R0, R1, R2, ar, (uint32_t)Vq);
      const int Vm = Vq + 12;
      uint32_t offm = (uint32_t)(b + 36 * Vq);
      uint64_t e0 = ext(sPos, offm), e1 = ext(sPos, offm + 64), e2 = ext(sPos, offm + 128);
      uint64_t mr = (((e0 & R0) | (e1 & R1) | (e2 & R2)) != 0ull) ? 1ull : 0ull;
      orAt(R0, R1, R2, mr, (uint32_t)Vm);
    }

    // backward liveness with on-the-fly R-masking (O ⊆ R)
    uint64_t O0 = ext(sPos, LMB)       & R0;
    uint64_t O1 = ext(sPos, LMB + 64)  & R1;
    uint64_t O2 = ext(sPos, LMB + 128) & ((1ull << 30) - 1ull) & R2;
    const int hg = g % 12;
#pragma unroll
    for (int L = NL - 1; L >= 0; --L) {
      const int Vq = 2 + 13 * L, Vm = Vq + 12;
      const int b  = c_base[L];
      if (rbit(O0, O1, O2, (uint32_t)Vm)) {
        uint64_t m0, m1, m2; maskLen((uint32_t)Vm, m0, m1, m2);
        uint32_t offm = (uint32_t)(b + 36 * Vq);
        O0 |= ext(sPos, offm)       & R0 & m0;
        O1 |= ext(sPos, offm + 64)  & R1 & m1;
        O2 |= ext(sPos, offm + 128) & R2 & m2;
      }
      uint32_t h12 = ext12(O0, O1, O2, (uint32_t)Vq);
      uint64_t q0, q1, q2; maskLen((uint32_t)Vq, q0, q1, q2);
      uint64_t c0 = 0ull, c1 = 0ull, c2 = 0ull;
      if (g < 36 && ((h12 >> hg) & 1u)) {
        uint32_t off = (uint32_t)(b + g * Vq);
        c0 = ext(sPos, off)       & R0 & q0;
        c1 = ext(sPos, off + 64)  & R1 & q1;
        c2 = ext(sPos, off + 128) & R2 & q2;
      }
#pragma unroll
      for (int d = 32; d; d >>= 1) {
        c0 |= __shfl_xor((unsigned long long)c0, d);
        c1 |= __shfl_xor((unsigned long long)c1, d);
        c2 |= __shfl_xor((unsigned long long)c2, d);
      }
      O0 |= c0; O1 |= c1; O2 |= c2;
    }
    if (lane == 0) {
      sLv[0] = R0 & O0; sLv[1] = R1 & O1; sLv[2] = R2 & O2; sLv[3] = 0ull;
    }
  }
  __syncthreads();

  // ---- Phase D: build keep bitvector via shifted live windows -------------
  {
    const uint64_t l0 = sLv[0], l1 = sLv[1], l2 = sLv[2];
    for (int s = tid; s < NSEG; s += TPB) {
      uint32_t p0, len;
      bool olive;
      if (s == NSEG - 1) {               // LM tail: keep[i] = live[i]
        p0 = LMB; len = 158; olive = true;
      } else {
        int L = s / 37, j = s - L * 37;
        int Vq = 2 + 13 * L, b = c_base[L];
        if (j < 36) { p0 = (uint32_t)(b + j * Vq); len = (uint32_t)Vq;
                      olive = rbit(l0, l1, l2, (uint32_t)(Vq + (j % 12))) != 0ull; }
        else        { p0 = (uint32_t)(b + 36 * Vq); len = (uint32_t)(Vq + 12);
                      olive = rbit(l0, l1, l2, (uint32_t)(Vq + 12)) != 0ull; }
      }
      if (!olive) continue;
      uint32_t w0 = p0 >> 6, s0 = p0 & 63;
      uint64_t first = l0;
      if (len < 64) first &= (1ull << len) - 1ull;
      atomicOr((unsigned long long*)&sKeep[w0], (unsigned long long)(first << s0));
      uint32_t done = 64 - s0;
      uint32_t w = w0 + 1;
      while (done < len) {
        uint64_t v = rext(l0, l1, l2, done);
        uint32_t rem = len - done;
        if (rem < 64) v &= (1ull << rem) - 1ull;
        atomicOr((unsigned long long*)&sKeep[w], (unsigned long long)v);
        done += 64; ++w;
      }
    }
  }
  __syncthreads();

  // ---- Phase F: select registered clipped m by keep bit + stream out ------
  // Param index of lane's element c: P = G*256 + 4*lane + c
  //   -> keep word G*4 + (lane>>4), bits 4*(lane&15)+c (nibble per lane).
  {
    const int sh = 4 * (lane & 15);
    const int kw0 = lane >> 4;
#pragma unroll
    for (int k = 0; k < NITER; ++k) {
      const int G = wv + k * NWV;
      if (G >= NGRP) continue;                   // wave-uniform
      int e4 = G * 64 + lane;
      bool inb = e4 < (PTOT / 4);
      uint32_t kb = (uint32_t)(sKeep[G * 4 + kw0] >> sh) & 0xFu;
      vf4 m = mv[k];
      if (inb) {
        vf4 o;
        o.x = (kb & 1u) ? m.x : 0.0f;
        o.y = (kb & 2u) ? m.y : 0.0f;
        o.z = (kb & 4u) ? m.z : 0.0f;
        o.w = (kb & 8u) ? m.w : 0.0f;
        __builtin_nontemporal_store(o, &op4[e4]);
      }
    }
  }
}

extern "C" void kernel_launch(void* const* d_in, const int* in_sizes, int n_in,
                              void* d_out, int out_size, void* d_ws, size_t ws_size,
                              hipStream_t stream) {
  const float* sp   = (const float*)d_in[0];
  const float* unif = (const float*)d_in[1];
  float* out = (float*)d_out;
  char* ws = (char*)d_ws;
  float* pr = (float*)ws;                                  // 132096 B
  float* wd = (float*)(ws + 132096);                       // 132096 B
  int bz = in_sizes[1] / PTOT;   // 1024

  init_tables<<<dim3(TPAD / 256), dim3(256), 0, stream>>>(sp, pr, wd);
  fused_kernel<<<dim3(bz), dim3(TPB), 0, stream>>>(
      unif, (const vf4*)pr, (const vf4*)wd, out);
}